// Round 12
// baseline (196.078 us; speedup 1.0000x reference)
//
#include <hip/hip_runtime.h>
#include <math.h>
#include <float.h>

#define NL      64
#define NOBS    400
#define NC      3000
#define HALF_NC 1500         // pairs per T (+1 sentinel task)
#define CHUNK   64
#define NCHUNK  24           // 24*64 = 1536 >= 1500 pairs + 1 sentinel
#define TWO_PI_F   6.2831853071795864769f
#define INV_2PI_F  0.15915494309189535f
#define LOG2E_F    1.4426950408889634f
#define LOG2_0P1  -3.3219280948873623f

typedef float fx2 __attribute__((ext_vector_type(2)));

__device__ __forceinline__ float hsin(float x)  { return __builtin_amdgcn_sinf(x); }
__device__ __forceinline__ float hcos(float x)  { return __builtin_amdgcn_cosf(x); }
__device__ __forceinline__ float hexp2(float x) { return __builtin_amdgcn_exp2f(x); }
__device__ __forceinline__ float hrcp(float x)  { return __builtin_amdgcn_rcpf(x); }
__device__ __forceinline__ float hsqrt(float x) { return __builtin_amdgcn_sqrtf(x); }

__device__ __forceinline__ fx2 v_sqrt(fx2 v) { fx2 r; r.x = hsqrt(v.x); r.y = hsqrt(v.y); return r; }
__device__ __forceinline__ fx2 v_rcp (fx2 v) { fx2 r; r.x = hrcp(v.x);  r.y = hrcp(v.y);  return r; }
__device__ __forceinline__ fx2 v_sin (fx2 v) { fx2 r; r.x = hsin(v.x);  r.y = hsin(v.y);  return r; }
__device__ __forceinline__ fx2 v_cos (fx2 v) { fx2 r; r.x = hcos(v.x);  r.y = hcos(v.y);  return r; }
__device__ __forceinline__ fx2 v_exp2(fx2 v) { fx2 r; r.x = hexp2(v.x); r.y = hexp2(v.y); return r; }
__device__ __forceinline__ fx2 v_abs (fx2 v) { fx2 r; r.x = fabsf(v.x); r.y = fabsf(v.y); return r; }
__device__ __forceinline__ fx2 v_max (fx2 a, fx2 b) { fx2 r; r.x = fmaxf(a.x, b.x); r.y = fmaxf(a.y, b.y); return r; }

// monotone float <-> uint encoding for atomic max/min
__device__ __forceinline__ unsigned enc(float f) {
    unsigned u = __float_as_uint(f);
    return (u & 0x80000000u) ? ~u : (u | 0x80000000u);
}
__device__ __forceinline__ float dec(unsigned k) {
    unsigned u = (k & 0x80000000u) ? (k & 0x7fffffffu) : ~k;
    return __uint_as_float(u);
}

// ---------------------------------------------------------------------------
// Kernel 1: Brocher b->(a,rho) + init atomic slots
// ---------------------------------------------------------------------------
__global__ void prep_kernel(const float* __restrict__ b, float* __restrict__ a_out,
                            float* __restrict__ rho_out,
                            unsigned* __restrict__ maxenc, unsigned* __restrict__ minenc) {
    int i = threadIdx.x;   // 256 threads
    if (i < NL) {
        float bb = b[i];
        float b2 = bb * bb, b3 = b2 * bb, b4 = b3 * bb;
        float a = 0.9409f + 2.0947f * bb - 0.8206f * b2 + 0.2683f * b3 - 0.0251f * b4;
        float a2 = a * a, a3 = a2 * a, a4 = a3 * a, a5 = a4 * a;
        float rho = 1.6612f * a - 0.4721f * a2 + 0.0671f * a3 - 0.0043f * a4 + 0.000106f * a5;
        a_out[i] = a;
        rho_out[i] = rho;
    }
    for (int j = i; j < NOBS; j += 256) {
        maxenc[j] = 0u;            // below enc of any finite float
        minenc[j] = 0xFFFFFFFFu;   // above enc of any finite float
    }
}

// ---------------------------------------------------------------------------
// Kernel 1b: per-(T,layer) parameter table (wave-uniform in det_kernel ->
// read via s_load into SGPRs; frees ~10 VGPRs vs LDS staging).
// Record (8 floats): [xka2, xkb2, gammk, dmsin, dmexp, rr, rr2, pad]
// tab2[2t] = omega, tab2[2t+1] = 1/rho[0]
// ---------------------------------------------------------------------------
__global__ void prep2_kernel(const float* __restrict__ tlist, const float* __restrict__ d,
                             const float* __restrict__ b,
                             const float* __restrict__ a_arr, const float* __restrict__ rho_arr,
                             float* __restrict__ tabL, float* __restrict__ tab2) {
    int t = blockIdx.x;    // NOBS blocks
    int m = threadIdx.x;   // 64 threads = 64 layers
    float omega = fmaxf(TWO_PI_F / tlist[t], 0.0001f);
    float am = a_arr[m], bm = b[m], dm = d[m];
    float ta = omega / am;
    float tb = omega / bm;
    float tt = bm / omega;
    float* P = tabL + t * (NL * 8) + m * 8;
    P[0] = ta * ta;
    P[1] = tb * tb;
    P[2] = 2.0f * tt * tt;
    P[3] = dm * INV_2PI_F;
    P[4] = -2.0f * LOG2E_F * dm;
    float rr = (m < NL - 1) ? (rho_arr[m] / rho_arr[m + 1]) : 1.0f;
    P[5] = rr;
    P[6] = rr * rr;
    P[7] = 0.0f;
    if (m == 0) {
        tab2[2 * t]     = omega;
        tab2[2 * t + 1] = 1.0f / rho_arr[0];
    }
}

// ---------------------------------------------------------------------------
// Dunkin layer step; P points into the global per-T table (uniform address).
// Tracks f = e * diag(1, rho, rho, rho, rho^2); 2 dets packed per lane (fx2),
// packed components are ADJACENT grid c values -> branch-uniform.
// ---------------------------------------------------------------------------

struct SideVals { float cosv, wv, xv, fv; };

__device__ __forceinline__ SideVals side_mixed(float ra, bool lt, float dmsin,
                                               float dmexp, float ir) {
    float s = hsin(ra * dmsin);
    float c = hcos(ra * dmsin);
    float f = hexp2(ra * dmexp);
    float se = 0.5f - 0.5f * f;
    SideVals r;
    r.cosv = lt ? c : (0.5f + 0.5f * f);
    r.wv = (lt ? s : se) * ir;
    r.xv = ra * (lt ? -s : se);
    r.fv = lt ? 1.0f : f;
    return r;
}

template <bool NORM>
__device__ __forceinline__ void layer_step(
    fx2& f0, fx2& f1, fx2& f2, fx2& f3, fx2& f4,
    const float* __restrict__ P, fx2 wvno2, fx2 t2) {

    float xka2 = P[0], xkb2 = P[1], gammk = P[2];
    float dmsin = P[3], dmexp = P[4];
    float rr = P[5], rr2 = P[6];

    // density-ratio prescale (D = S_{m+1}^{-1} S_m)
    f1 *= rr; f2 *= rr; f3 *= rr; f4 *= rr2;

    fx2 ra2 = wvno2 - xka2;
    fx2 rb2 = wvno2 - xkb2;
    fx2 ra = v_sqrt(v_abs(ra2));
    fx2 rb = v_sqrt(v_abs(rb2));
    fx2 gam = gammk * wvno2;

    bool px = ra2.x < 0.0f, py = ra2.y < 0.0f;   // propagating P
    bool sx = rb2.x < 0.0f, sy = rb2.y < 0.0f;   // propagating S

    fx2 ra_s = v_max(ra, (fx2)1e-18f);
    fx2 rb_s = v_max(rb, (fx2)1e-18f);
    fx2 rp  = v_rcp(ra_s * rb_s);
    fx2 ira = rb_s * rp;
    fx2 irb = ra_s * rp;

    bool allP_prop = __all(px && py);
    bool allP_evan = __all(!(px || py));
    bool allS_prop = __all(sx && sy);
    bool allS_evan = __all(!(sx || sy));

    // ---- P side ----
    fx2 cosp, w, x, fp;
    if (allP_prop) {
        fx2 arg = ra * dmsin;
        fx2 s = v_sin(arg);
        cosp = v_cos(arg);
        w = s * ira;
        x = -(ra * s);
        fp = (fx2)1.0f;
    } else if (allP_evan) {
        fx2 f = v_exp2(ra * dmexp);
        fx2 se = 0.5f - 0.5f * f;
        cosp = 0.5f + 0.5f * f;
        w = se * ira;
        x = ra * se;
        fp = f;
    } else {
        SideVals vx = side_mixed(ra.x, px, dmsin, dmexp, ira.x);
        SideVals vy = side_mixed(ra.y, py, dmsin, dmexp, ira.y);
        cosp.x = vx.cosv; w.x = vx.wv; x.x = vx.xv; fp.x = vx.fv;
        cosp.y = vy.cosv; w.y = vy.wv; x.y = vy.xv; fp.y = vy.fv;
    }

    // ---- S side ----
    fx2 cosq, y, z, fq;
    if (allS_prop) {
        fx2 arg = rb * dmsin;
        fx2 s = v_sin(arg);
        cosq = v_cos(arg);
        y = s * irb;
        z = -(rb * s);
        fq = (fx2)1.0f;
    } else if (allS_evan) {
        fx2 f = v_exp2(rb * dmexp);
        fx2 se = 0.5f - 0.5f * f;
        cosq = 0.5f + 0.5f * f;
        y = se * irb;
        z = rb * se;
        fq = f;
    } else {
        SideVals vx = side_mixed(rb.x, sx, dmsin, dmexp, irb.x);
        SideVals vy = side_mixed(rb.y, sy, dmsin, dmexp, irb.y);
        cosq.x = vx.cosv; y.x = vx.wv; z.x = vx.xv; fq.x = vx.fv;
        cosq.y = vy.cosv; y.y = vy.wv; z.y = vy.xv; fq.y = vy.fv;
    }

    // a0 = exp(-(pex+sex)) == sqrt(fp*fq); both-prop => exactly 1 (skip sqrt)
    fx2 a0;
    if (allP_prop && allS_prop) {
        a0 = (fx2)1.0f;
    } else {
        a0 = v_sqrt(fp * fq);
    }

    fx2 cpcq = cosp * cosq;
    fx2 cpy = cosp * y, cpz = cosp * z;
    fx2 cqw = cosq * w, cqx = cosq * x;
    fx2 xy = x * y, xz = x * z, wy = w * y, wz = w * z;

    fx2 gamm1 = gam - 1.0f;
    fx2 twgm1 = gam + gamm1;
    fx2 gmgmk = gam * gammk;
    fx2 gmgm1 = gam * gamm1;
    fx2 gm1sq = gamm1 * gamm1;

    fx2 a0pq  = a0 - cpcq;
    fx2 a0pq2 = a0pq + a0pq;
    fx2 nwy   = wvno2 * wy;
    fx2 gw    = gm1sq * wy;

    // rm-free C' entries (nc* are the negated forms)
    fx2 c00  = cpcq - gmgm1 * a0pq2 - gmgmk * xz - gm1sq * nwy;
    fx2 c01  = wvno2 * cpy - cqx;
    fx2 nc02 = twgm1 * a0pq + gammk * xz + gamm1 * nwy;
    fx2 c03  = cpz - wvno2 * cqw;
    fx2 nc04 = wvno2 * a0pq2 + xz + wvno2 * nwy;
    fx2 c10  = gmgmk * cpz - gm1sq * cqw;
    fx2 c12  = gammk * cpz - gamm1 * cqw;
    fx2 c30  = gm1sq * cpy - gmgmk * cqx;
    fx2 c32  = gamm1 * cpy - gammk * cqx;
    fx2 t40  = gm1sq * a0pq2 + gmgmk * xz;
    fx2 nc40 = gmgmk * t40 + gm1sq * gw;
    fx2 th   = gmgm1 * twgm1;
    fx2 nc42 = th * a0pq + (gmgmk * gammk) * xz + gamm1 * gw;
    fx2 c22  = a0 + 2.0f * (cpcq - c00);

    fx2 e2t = f2 * t2;   // row 2 of C' = t2 * {-nc42, c32, .., c12, -nc02}

    fx2 ee0 =  f0 * c00  + f1 * c10  - e2t * nc42 + f3 * c30  - f4 * nc40;
    fx2 ee1 =  f0 * c01  + f1 * cpcq + e2t * c32  - f3 * xy   + f4 * c30;
    fx2 ee2 = -f0 * nc02 + f1 * c12  + f2 * c22   + f3 * c32  - f4 * nc42;
    fx2 ee3 =  f0 * c03  - f1 * wz   + e2t * c12  + f3 * cpcq + f4 * c10;
    fx2 ee4 = -f0 * nc04 + f1 * c03  - e2t * nc02 + f3 * c01  + f4 * c00;

    if (NORM) {
        fx2 nv = v_max(v_max(v_abs(ee0), v_abs(ee1)), v_max(v_abs(ee2), v_abs(ee3)));
        nv = v_max(nv, v_abs(ee4));
        nv = v_max(nv, (fx2)1e-30f);
        // exact power-of-2 inverse of nrm's exponent (no rcp, no rounding)
        fx2 inv;
        inv.x = __uint_as_float(0x7f000000u - (__float_as_uint(nv.x) & 0x7f800000u));
        inv.y = __uint_as_float(0x7f000000u - (__float_as_uint(nv.y) & 0x7f800000u));
        f0 = ee0 * inv; f1 = ee1 * inv; f2 = ee2 * inv; f3 = ee3 * inv; f4 = ee4 * inv;
    } else {
        f0 = ee0; f1 = ee1; f2 = ee2; f3 = ee3; f4 = ee4;
    }
}

__device__ fx2 det_eval(fx2 cvel, float omega, const float* __restrict__ T, float ir0) {
    fx2 wvno  = omega * v_rcp(cvel);
    fx2 wvno2 = wvno * wvno;
    fx2 t2    = -2.0f * wvno2;

    // halfspace (layer NL-1), rho factors dropped (global scale is irrelevant)
    const float* P = &T[(NL - 1) * 8];
    fx2 ra = v_sqrt(v_abs(wvno2 - P[0]));
    fx2 rb = v_sqrt(v_abs(wvno2 - P[1]));
    float gammk = P[2];
    fx2 gam = gammk * wvno2;
    fx2 gamm1 = gam - 1.0f;
    fx2 rarb = ra * rb;

    fx2 f0 = gamm1 * gamm1 - gam * gammk * rarb;
    fx2 f1 = -ra;
    fx2 f2 = gamm1 - gammk * rarb;
    fx2 f3 = rb;
    fx2 f4 = wvno2 - rarb;

    // 63 layers: 20 triplets (62..3) with norm on 3rd, then 2,1,0 plain.
    #pragma unroll 1
    for (int m = NL - 2; m >= 5; m -= 3) {
        layer_step<false>(f0, f1, f2, f3, f4, &T[m * 8], wvno2, t2);
        layer_step<false>(f0, f1, f2, f3, f4, &T[(m - 1) * 8], wvno2, t2);
        layer_step<true >(f0, f1, f2, f3, f4, &T[(m - 2) * 8], wvno2, t2);
    }
    layer_step<false>(f0, f1, f2, f3, f4, &T[2 * 8], wvno2, t2);
    layer_step<false>(f0, f1, f2, f3, f4, &T[1 * 8], wvno2, t2);
    layer_step<false>(f0, f1, f2, f3, f4, &T[0 * 8], wvno2, t2);

    // unscale to e-space (S_0 = diag(1, r0, r0, r0, r0^2)) and final max-norm
    fx2 res;
    {
        float m123 = fmaxf(fmaxf(fabsf(f1.x), fabsf(f2.x)), fabsf(f3.x)) * ir0;
        float nrm = fmaxf(fabsf(f0.x), fmaxf(m123, fabsf(f4.x) * (ir0 * ir0)));
        res.x = f0.x * hrcp(nrm);
    }
    {
        float m123 = fmaxf(fmaxf(fabsf(f1.y), fabsf(f2.y)), fabsf(f3.y)) * ir0;
        float nrm = fmaxf(fabsf(f0.y), fmaxf(m123, fabsf(f4.y) * (ir0 * ir0)));
        res.y = f0.y * hrcp(nrm);
    }
    return res;
}

// ---------------------------------------------------------------------------
// Kernel 2: two ADJACENT dets per thread (packed); 1-wave blocks; no LDS;
// layer params via uniform s_load from tabL. grid = (NCHUNK, NOBS).
// idx==HALF_NC is the (vlist[t]) sentinel.
// __launch_bounds__(64,10): VGPR cap 51 -> 10 wave slots/SIMD so all ~9.4
// waves/SIMD of work are co-resident (single round, no quantization tail).
// Round-10 lesson: cap 32 spilled; 51 is a mild squeeze from natural ~55.
// ---------------------------------------------------------------------------
__global__ __launch_bounds__(64, 10) void det_kernel(
    const float* __restrict__ vlist, const float* __restrict__ Clist,
    const float* __restrict__ tabL, const float* __restrict__ tab2,
    unsigned* __restrict__ maxenc, unsigned* __restrict__ minenc,
    float* __restrict__ e00vals) {

    int t     = blockIdx.y;
    int chunk = blockIdx.x;
    int tid   = threadIdx.x;   // 0..63

    const float* __restrict__ T = tabL + t * (NL * 8);
    float omega = tab2[2 * t];        // uniform -> SGPR
    float ir0   = tab2[2 * t + 1];

    int idx = chunk * CHUNK + tid;
    float lmax = -FLT_MAX, lmin = FLT_MAX;

    if (idx <= HALF_NC) {
        bool grid_pt = idx < HALF_NC;
        fx2 cv;
        if (grid_pt) {
            cv.x = Clist[2 * idx];
            cv.y = Clist[2 * idx + 1];
        } else {
            float v = vlist[t];
            cv.x = v; cv.y = v;
        }
        fx2 det = det_eval(cv, omega, T, ir0);
        if (grid_pt) {
            lmax = fmaxf(det.x, det.y);
            lmin = fminf(det.x, det.y);
        } else {
            e00vals[t] = det.x;
        }
    }

    // wave-level butterfly reduce (64 lanes)
    #pragma unroll
    for (int off = 32; off >= 1; off >>= 1) {
        lmax = fmaxf(lmax, __shfl_xor(lmax, off));
        lmin = fminf(lmin, __shfl_xor(lmin, off));
    }
    if (tid == 0) {
        atomicMax(&maxenc[t], enc(lmax));
        atomicMin(&minenc[t], enc(lmin));
    }
}

// ---------------------------------------------------------------------------
// Kernel 3: combine, misfit transform, damping, final sum
// ---------------------------------------------------------------------------
__global__ __launch_bounds__(512) void finalize_kernel(
    const float* __restrict__ b,
    const unsigned* __restrict__ maxenc, const unsigned* __restrict__ minenc,
    const float* __restrict__ e00vals, float* __restrict__ out) {

    int tid = threadIdx.x;
    float acc = 0.0f;

    if (tid < NOBS) {
        float mx = dec(maxenc[tid]);
        float mn = dec(minenc[tid]);
        float rng  = mx - mn;
        float e00  = e00vals[tid] / rng;
        float term = exp2f(LOG2_0P1 * fabsf(e00)) - 1.0f;  // 0.1^|e00| - 1
        acc = fabsf(term) * (1.0f / (float)NOBS);
    }
    if (tid < NL) {
        float bi = b[tid];
        float lb;
        if (tid == 0)            lb = bi - b[1];
        else if (tid == NL - 1)  lb = bi - b[NL - 2];
        else                     lb = 2.0f * bi - b[tid - 1] - b[tid + 1];
        acc += fabsf(lb * (1.0f / (float)NL));   // DAMP = 1.0
    }

    __shared__ float s[512];
    s[tid] = acc;
    __syncthreads();
    for (int st = 256; st > 0; st >>= 1) {
        if (tid < st) s[tid] += s[tid + st];
        __syncthreads();
    }
    if (tid == 0) out[0] = s[0];
}

// ---------------------------------------------------------------------------
extern "C" void kernel_launch(void* const* d_in, const int* in_sizes, int n_in,
                              void* d_out, int out_size, void* d_ws, size_t ws_size,
                              hipStream_t stream) {
    const float* vlist = (const float*)d_in[0];
    const float* tlist = (const float*)d_in[1];
    const float* d     = (const float*)d_in[2];
    const float* b     = (const float*)d_in[3];
    const float* Clist = (const float*)d_in[4];
    float* out = (float*)d_out;

    float*    ws      = (float*)d_ws;
    float*    a_arr   = ws;                       // 64
    float*    rho_arr = ws + 64;                  // 64
    float*    e00v    = ws + 128;                 // 400
    unsigned* maxenc  = (unsigned*)(ws + 528);    // 400
    unsigned* minenc  = (unsigned*)(ws + 928);    // 400
    float*    tab2    = ws + 1328;                // 800
    float*    tabL    = ws + 2128;                // 400*64*8 = 204800 (~824 KB total)

    prep_kernel<<<1, 256, 0, stream>>>(b, a_arr, rho_arr, maxenc, minenc);
    prep2_kernel<<<NOBS, 64, 0, stream>>>(tlist, d, b, a_arr, rho_arr, tabL, tab2);
    det_kernel<<<dim3(NCHUNK, NOBS), 64, 0, stream>>>(vlist, Clist, tabL, tab2,
                                                      maxenc, minenc, e00v);
    finalize_kernel<<<1, 512, 0, stream>>>(b, maxenc, minenc, e00v, out);
}

// Round 13
// 180.936 us; speedup vs baseline: 1.0837x; 1.0837x over previous
//
#include <hip/hip_runtime.h>
#include <math.h>
#include <float.h>

#define NL      64
#define NOBS    400
#define NC      3000
#define HALF_NC 1500         // pairs per T (+1 sentinel task)
#define CHUNK   256
#define NCHUNK  6            // 6*256 = 1536 >= 1500 pairs + 1 sentinel
#define TWO_PI_F   6.2831853071795864769f
#define INV_2PI_F  0.15915494309189535f
#define LOG2E_F    1.4426950408889634f
#define LOG2_0P1  -3.3219280948873623f

typedef float fx2 __attribute__((ext_vector_type(2)));

__device__ __forceinline__ float hsin(float x)  { return __builtin_amdgcn_sinf(x); }
__device__ __forceinline__ float hcos(float x)  { return __builtin_amdgcn_cosf(x); }
__device__ __forceinline__ float hexp2(float x) { return __builtin_amdgcn_exp2f(x); }
__device__ __forceinline__ float hrcp(float x)  { return __builtin_amdgcn_rcpf(x); }
__device__ __forceinline__ float hrsq(float x)  { return __builtin_amdgcn_rsqf(x); }

__device__ __forceinline__ fx2 v_rsq (fx2 v) { fx2 r; r.x = hrsq(v.x);  r.y = hrsq(v.y);  return r; }
__device__ __forceinline__ fx2 v_rcp (fx2 v) { fx2 r; r.x = hrcp(v.x);  r.y = hrcp(v.y);  return r; }
__device__ __forceinline__ fx2 v_sin (fx2 v) { fx2 r; r.x = hsin(v.x);  r.y = hsin(v.y);  return r; }
__device__ __forceinline__ fx2 v_cos (fx2 v) { fx2 r; r.x = hcos(v.x);  r.y = hcos(v.y);  return r; }
__device__ __forceinline__ fx2 v_exp2(fx2 v) { fx2 r; r.x = hexp2(v.x); r.y = hexp2(v.y); return r; }
__device__ __forceinline__ fx2 v_abs (fx2 v) { fx2 r; r.x = fabsf(v.x); r.y = fabsf(v.y); return r; }
__device__ __forceinline__ fx2 v_max (fx2 a, fx2 b) { fx2 r; r.x = fmaxf(a.x, b.x); r.y = fmaxf(a.y, b.y); return r; }

// monotone float <-> uint encoding for atomic max/min
__device__ __forceinline__ unsigned enc(float f) {
    unsigned u = __float_as_uint(f);
    return (u & 0x80000000u) ? ~u : (u | 0x80000000u);
}
__device__ __forceinline__ float dec(unsigned k) {
    unsigned u = (k & 0x80000000u) ? (k & 0x7fffffffu) : ~k;
    return __uint_as_float(u);
}

// ---------------------------------------------------------------------------
// Kernel 1: Brocher b->(a,rho) + init atomic slots
// ---------------------------------------------------------------------------
__global__ void prep_kernel(const float* __restrict__ b, float* __restrict__ a_out,
                            float* __restrict__ rho_out,
                            unsigned* __restrict__ maxenc, unsigned* __restrict__ minenc) {
    int i = threadIdx.x;   // 256 threads
    if (i < NL) {
        float bb = b[i];
        float b2 = bb * bb, b3 = b2 * bb, b4 = b3 * bb;
        float a = 0.9409f + 2.0947f * bb - 0.8206f * b2 + 0.2683f * b3 - 0.0251f * b4;
        float a2 = a * a, a3 = a2 * a, a4 = a3 * a, a5 = a4 * a;
        float rho = 1.6612f * a - 0.4721f * a2 + 0.0671f * a3 - 0.0043f * a4 + 0.000106f * a5;
        a_out[i] = a;
        rho_out[i] = rho;
    }
    for (int j = i; j < NOBS; j += 256) {
        maxenc[j] = 0u;            // below enc of any finite float
        minenc[j] = 0xFFFFFFFFu;   // above enc of any finite float
    }
}

// ---------------------------------------------------------------------------
// Layer record (8 floats in LDS):
// [0]=xka2 [1]=xkb2 [2]=gammk [3]=dms(dm/2pi) [4]=dmeh(-log2e*dm, HALF exp arg)
// [5]=rho_ratio [6]=ratio^2 [7]=pad
// Tracks f = e * diag(1, rho, rho, rho, rho^2); 2 dets packed per lane (fx2),
// packed components are ADJACENT grid c values -> branch-uniform.
// Trans diet: ira/irb via v_rsq (no sqrt+rcp); evanescent uses g=exp2(half),
// fac=g*g, and a0 = gP*gQ (no sqrt).
// ---------------------------------------------------------------------------

struct SideVals { float cosv, wv, xv, gv; };

// mixed propagating/evanescent side, one component (returns by value)
__device__ __forceinline__ SideVals side_mixed(float ra, bool lt, float dms,
                                               float dmeh, float ir) {
    float s = hsin(ra * dms);
    float c = hcos(ra * dms);
    float g = hexp2(ra * dmeh);
    float f = g * g;
    float se = 0.5f - 0.5f * f;
    SideVals r;
    r.cosv = lt ? c : (0.5f + 0.5f * f);
    r.wv = (lt ? s : se) * ir;
    r.xv = ra * (lt ? -s : se);
    r.gv = lt ? 1.0f : g;
    return r;
}

template <bool NORM>
__device__ __forceinline__ void layer_step(
    fx2& f0, fx2& f1, fx2& f2, fx2& f3, fx2& f4,
    const float* __restrict__ P, fx2 wvno2, fx2 t2) {

    float xka2 = P[0], xkb2 = P[1], gammk = P[2];
    float dms = P[3], dmeh = P[4];
    float rr = P[5], rr2 = P[6];

    // density-ratio prescale (D = S_{m+1}^{-1} S_m)
    f1 *= rr; f2 *= rr; f3 *= rr; f4 *= rr2;

    fx2 ra2 = wvno2 - xka2;
    fx2 rb2 = wvno2 - xkb2;
    fx2 ra2a = v_max(v_abs(ra2), (fx2)1e-30f);
    fx2 rb2a = v_max(v_abs(rb2), (fx2)1e-30f);
    fx2 ira = v_rsq(ra2a);
    fx2 irb = v_rsq(rb2a);
    fx2 ra = ra2a * ira;
    fx2 rb = rb2a * irb;
    fx2 gam = gammk * wvno2;

    bool px = ra2.x < 0.0f, py = ra2.y < 0.0f;   // propagating P
    bool sx = rb2.x < 0.0f, sy = rb2.y < 0.0f;   // propagating S

    bool allP_prop = __all(px && py);
    bool allP_evan = __all(!(px || py));
    bool allS_prop = __all(sx && sy);
    bool allS_evan = __all(!(sx || sy));

    // ---- P side ----
    fx2 cosp, w, x, gp;
    if (allP_prop) {
        fx2 arg = ra * dms;
        fx2 s = v_sin(arg);
        cosp = v_cos(arg);
        w = s * ira;
        x = -(ra * s);
        gp = (fx2)1.0f;
    } else if (allP_evan) {
        fx2 g = v_exp2(ra * dmeh);
        fx2 f = g * g;
        fx2 se = 0.5f - 0.5f * f;
        cosp = 0.5f + 0.5f * f;
        w = se * ira;
        x = ra * se;
        gp = g;
    } else {
        SideVals vx = side_mixed(ra.x, px, dms, dmeh, ira.x);
        SideVals vy = side_mixed(ra.y, py, dms, dmeh, ira.y);
        cosp.x = vx.cosv; w.x = vx.wv; x.x = vx.xv; gp.x = vx.gv;
        cosp.y = vy.cosv; w.y = vy.wv; x.y = vy.xv; gp.y = vy.gv;
    }

    // ---- S side ----
    fx2 cosq, y, z, gq;
    if (allS_prop) {
        fx2 arg = rb * dms;
        fx2 s = v_sin(arg);
        cosq = v_cos(arg);
        y = s * irb;
        z = -(rb * s);
        gq = (fx2)1.0f;
    } else if (allS_evan) {
        fx2 g = v_exp2(rb * dmeh);
        fx2 f = g * g;
        fx2 se = 0.5f - 0.5f * f;
        cosq = 0.5f + 0.5f * f;
        y = se * irb;
        z = rb * se;
        gq = g;
    } else {
        SideVals vx = side_mixed(rb.x, sx, dms, dmeh, irb.x);
        SideVals vy = side_mixed(rb.y, sy, dms, dmeh, irb.y);
        cosq.x = vx.cosv; y.x = vx.wv; z.x = vx.xv; gq.x = vx.gv;
        cosq.y = vy.cosv; y.y = vy.wv; z.y = vy.xv; gq.y = vy.gv;
    }

    // a0 = exp(-(pex+sex)) == gp*gq (g = exp(-p) iff evanescent, else 1)
    fx2 a0;
    if (allP_prop && allS_prop) {
        a0 = (fx2)1.0f;
    } else {
        a0 = gp * gq;
    }

    fx2 cpcq = cosp * cosq;
    fx2 cpy = cosp * y, cpz = cosp * z;
    fx2 cqw = cosq * w, cqx = cosq * x;
    fx2 xy = x * y, xz = x * z, wy = w * y, wz = w * z;

    fx2 gamm1 = gam - 1.0f;
    fx2 twgm1 = gam + gamm1;
    fx2 gmgmk = gam * gammk;
    fx2 gmgm1 = gam * gamm1;
    fx2 gm1sq = gamm1 * gamm1;

    fx2 a0pq  = a0 - cpcq;
    fx2 a0pq2 = a0pq + a0pq;
    fx2 nwy   = wvno2 * wy;
    fx2 gw    = gm1sq * wy;

    // rm-free C' entries (nc* are the negated forms)
    fx2 c00  = cpcq - gmgm1 * a0pq2 - gmgmk * xz - gm1sq * nwy;
    fx2 c01  = wvno2 * cpy - cqx;
    fx2 nc02 = twgm1 * a0pq + gammk * xz + gamm1 * nwy;
    fx2 c03  = cpz - wvno2 * cqw;
    fx2 nc04 = wvno2 * a0pq2 + xz + wvno2 * nwy;
    fx2 c10  = gmgmk * cpz - gm1sq * cqw;
    fx2 c12  = gammk * cpz - gamm1 * cqw;
    fx2 c30  = gm1sq * cpy - gmgmk * cqx;
    fx2 c32  = gamm1 * cpy - gammk * cqx;
    fx2 t40  = gm1sq * a0pq2 + gmgmk * xz;
    fx2 nc40 = gmgmk * t40 + gm1sq * gw;
    fx2 th   = gmgm1 * twgm1;
    fx2 nc42 = th * a0pq + (gmgmk * gammk) * xz + gamm1 * gw;
    fx2 c22  = a0 + 2.0f * (cpcq - c00);

    fx2 e2t = f2 * t2;   // row 2 of C' = t2 * {-nc42, c32, .., c12, -nc02}

    fx2 ee0 =  f0 * c00  + f1 * c10  - e2t * nc42 + f3 * c30  - f4 * nc40;
    fx2 ee1 =  f0 * c01  + f1 * cpcq + e2t * c32  - f3 * xy   + f4 * c30;
    fx2 ee2 = -f0 * nc02 + f1 * c12  + f2 * c22   + f3 * c32  - f4 * nc42;
    fx2 ee3 =  f0 * c03  - f1 * wz   + e2t * c12  + f3 * cpcq + f4 * c10;
    fx2 ee4 = -f0 * nc04 + f1 * c03  - e2t * nc02 + f3 * c01  + f4 * c00;

    if (NORM) {
        fx2 nv = v_max(v_max(v_abs(ee0), v_abs(ee1)), v_max(v_abs(ee2), v_abs(ee3)));
        nv = v_max(nv, v_abs(ee4));
        nv = v_max(nv, (fx2)1e-30f);
        // exact power-of-2 inverse of nrm's exponent (no rcp, no rounding)
        fx2 inv;
        inv.x = __uint_as_float(0x7f000000u - (__float_as_uint(nv.x) & 0x7f800000u));
        inv.y = __uint_as_float(0x7f000000u - (__float_as_uint(nv.y) & 0x7f800000u));
        f0 = ee0 * inv; f1 = ee1 * inv; f2 = ee2 * inv; f3 = ee3 * inv; f4 = ee4 * inv;
    } else {
        f0 = ee0; f1 = ee1; f2 = ee2; f3 = ee3; f4 = ee4;
    }
}

__device__ fx2 det_eval(fx2 cvel, float omega, const float* __restrict__ Lf, float ir0) {
    fx2 wvno  = omega * v_rcp(cvel);
    fx2 wvno2 = wvno * wvno;
    fx2 t2    = -2.0f * wvno2;

    // halfspace (layer NL-1), rho factors dropped (global scale is irrelevant)
    const float* P = &Lf[(NL - 1) * 8];
    fx2 ra2a = v_max(v_abs(wvno2 - P[0]), (fx2)1e-30f);
    fx2 rb2a = v_max(v_abs(wvno2 - P[1]), (fx2)1e-30f);
    fx2 ra = ra2a * v_rsq(ra2a);
    fx2 rb = rb2a * v_rsq(rb2a);
    float gammk = P[2];
    fx2 gam = gammk * wvno2;
    fx2 gamm1 = gam - 1.0f;
    fx2 rarb = ra * rb;

    fx2 f0 = gamm1 * gamm1 - gam * gammk * rarb;
    fx2 f1 = -ra;
    fx2 f2 = gamm1 - gammk * rarb;
    fx2 f3 = rb;
    fx2 f4 = wvno2 - rarb;

    // 63 layers: 20 triplets (62..3) with norm on 3rd, then 2,1,0 plain.
    #pragma unroll 1
    for (int m = NL - 2; m >= 5; m -= 3) {
        layer_step<false>(f0, f1, f2, f3, f4, &Lf[m * 8], wvno2, t2);
        layer_step<false>(f0, f1, f2, f3, f4, &Lf[(m - 1) * 8], wvno2, t2);
        layer_step<true >(f0, f1, f2, f3, f4, &Lf[(m - 2) * 8], wvno2, t2);
    }
    layer_step<false>(f0, f1, f2, f3, f4, &Lf[2 * 8], wvno2, t2);
    layer_step<false>(f0, f1, f2, f3, f4, &Lf[1 * 8], wvno2, t2);
    layer_step<false>(f0, f1, f2, f3, f4, &Lf[0 * 8], wvno2, t2);

    // unscale to e-space (S_0 = diag(1, r0, r0, r0, r0^2)) and final max-norm
    fx2 res;
    {
        float m123 = fmaxf(fmaxf(fabsf(f1.x), fabsf(f2.x)), fabsf(f3.x)) * ir0;
        float nrm = fmaxf(fabsf(f0.x), fmaxf(m123, fabsf(f4.x) * (ir0 * ir0)));
        res.x = f0.x * hrcp(nrm);
    }
    {
        float m123 = fmaxf(fmaxf(fabsf(f1.y), fabsf(f2.y)), fabsf(f3.y)) * ir0;
        float nrm = fmaxf(fabsf(f0.y), fmaxf(m123, fabsf(f4.y) * (ir0 * ir0)));
        res.y = f0.y * hrcp(nrm);
    }
    return res;
}

// ---------------------------------------------------------------------------
// Kernel 2: two ADJACENT dets per thread (packed); wave-reduce max/min;
// atomics per wave. grid = (NCHUNK, NOBS), block = 256.
// idx==HALF_NC is the (vlist[t]) sentinel.
// NOTE: min-waves left at 2 — forcing higher squeezed VGPR to 32 and caused
// a scratch-spill storm (Round 10: 3.3 GB HBM traffic, 4.6x slower).
// ---------------------------------------------------------------------------
__global__ __launch_bounds__(256, 2) void det_kernel(
    const float* __restrict__ vlist, const float* __restrict__ tlist,
    const float* __restrict__ d, const float* __restrict__ b,
    const float* __restrict__ Clist,
    const float* __restrict__ a_arr, const float* __restrict__ rho_arr,
    unsigned* __restrict__ maxenc, unsigned* __restrict__ minenc,
    float* __restrict__ e00vals) {

    __shared__ float Lf[NL * 8];
    __shared__ float s_ir0;

    int t     = blockIdx.y;
    int chunk = blockIdx.x;
    int tid   = threadIdx.x;

    float omega = fmaxf(TWO_PI_F / tlist[t], 0.0001f);

    if (tid < NL) {
        float am = a_arr[tid];
        float bm = b[tid];
        float dm = d[tid];
        float* P = &Lf[tid * 8];
        float ta = omega / am;
        float tb = omega / bm;
        P[0] = ta * ta;
        P[1] = tb * tb;
        float tt = bm / omega;
        P[2] = 2.0f * tt * tt;
        P[3] = dm * INV_2PI_F;
        P[4] = -LOG2E_F * dm;          // HALF exponential argument
        float rr = (tid < NL - 1) ? (rho_arr[tid] / rho_arr[tid + 1]) : 1.0f;
        P[5] = rr;
        P[6] = rr * rr;
        P[7] = 0.0f;
        if (tid == 0) s_ir0 = 1.0f / rho_arr[0];
    }
    __syncthreads();

    int idx = chunk * CHUNK + tid;
    float lmax = -FLT_MAX, lmin = FLT_MAX;

    if (idx <= HALF_NC) {
        bool grid_pt = idx < HALF_NC;
        fx2 cv;
        if (grid_pt) {
            // adjacent c values: branch-uniform packed components
            cv.x = Clist[2 * idx];
            cv.y = Clist[2 * idx + 1];
        } else {
            float v = vlist[t];
            cv.x = v; cv.y = v;
        }
        fx2 det = det_eval(cv, omega, Lf, s_ir0);
        if (grid_pt) {
            lmax = fmaxf(det.x, det.y);
            lmin = fminf(det.x, det.y);
        } else {
            e00vals[t] = det.x;
        }
    }

    // wave-level butterfly reduce (64 lanes)
    #pragma unroll
    for (int off = 32; off >= 1; off >>= 1) {
        lmax = fmaxf(lmax, __shfl_xor(lmax, off));
        lmin = fminf(lmin, __shfl_xor(lmin, off));
    }
    if ((tid & 63) == 0) {
        atomicMax(&maxenc[t], enc(lmax));
        atomicMin(&minenc[t], enc(lmin));
    }
}

// ---------------------------------------------------------------------------
// Kernel 3: combine, misfit transform, damping, final sum
// ---------------------------------------------------------------------------
__global__ __launch_bounds__(512) void finalize_kernel(
    const float* __restrict__ b,
    const unsigned* __restrict__ maxenc, const unsigned* __restrict__ minenc,
    const float* __restrict__ e00vals, float* __restrict__ out) {

    int tid = threadIdx.x;
    float acc = 0.0f;

    if (tid < NOBS) {
        float mx = dec(maxenc[tid]);
        float mn = dec(minenc[tid]);
        float rng  = mx - mn;
        float e00  = e00vals[tid] / rng;
        float term = exp2f(LOG2_0P1 * fabsf(e00)) - 1.0f;  // 0.1^|e00| - 1
        acc = fabsf(term) * (1.0f / (float)NOBS);
    }
    if (tid < NL) {
        float bi = b[tid];
        float lb;
        if (tid == 0)            lb = bi - b[1];
        else if (tid == NL - 1)  lb = bi - b[NL - 2];
        else                     lb = 2.0f * bi - b[tid - 1] - b[tid + 1];
        acc += fabsf(lb * (1.0f / (float)NL));   // DAMP = 1.0
    }

    __shared__ float s[512];
    s[tid] = acc;
    __syncthreads();
    for (int st = 256; st > 0; st >>= 1) {
        if (tid < st) s[tid] += s[tid + st];
        __syncthreads();
    }
    if (tid == 0) out[0] = s[0];
}

// ---------------------------------------------------------------------------
extern "C" void kernel_launch(void* const* d_in, const int* in_sizes, int n_in,
                              void* d_out, int out_size, void* d_ws, size_t ws_size,
                              hipStream_t stream) {
    const float* vlist = (const float*)d_in[0];
    const float* tlist = (const float*)d_in[1];
    const float* d     = (const float*)d_in[2];
    const float* b     = (const float*)d_in[3];
    const float* Clist = (const float*)d_in[4];
    float* out = (float*)d_out;

    float*    ws      = (float*)d_ws;
    float*    a_arr   = ws;                       // 64
    float*    rho_arr = ws + 64;                  // 64
    float*    e00v    = ws + 128;                 // 400
    unsigned* maxenc  = (unsigned*)(ws + 528);    // 400
    unsigned* minenc  = (unsigned*)(ws + 928);    // 400   (total ~5.3 KB)

    prep_kernel<<<1, 256, 0, stream>>>(b, a_arr, rho_arr, maxenc, minenc);
    det_kernel<<<dim3(NCHUNK, NOBS), 256, 0, stream>>>(vlist, tlist, d, b, Clist,
                                                       a_arr, rho_arr, maxenc, minenc, e00v);
    finalize_kernel<<<1, 512, 0, stream>>>(b, maxenc, minenc, e00v, out);
}